// Round 4
// baseline (294.470 us; speedup 1.0000x reference)
//
#include <hip/hip_runtime.h>

typedef unsigned short u16;
typedef unsigned int u32;
typedef __attribute__((ext_vector_type(8))) short bf16x8;
typedef __attribute__((ext_vector_type(4))) float f32x4;
typedef __attribute__((ext_vector_type(2))) unsigned int u32x2;

#define LOG2E 1.4426950408889634f

__device__ __forceinline__ u16 f2bf(float f) {
    u32 u = __float_as_uint(f);
    u += 0x7fffu + ((u >> 16) & 1u);
    return (u16)(u >> 16);
}
__device__ __forceinline__ float bf2f(u16 s) {
    return __uint_as_float(((u32)s) << 16);
}
// pack two f32 -> two truncated bf16 in one v_perm (hi in bits 31:16, lo in 15:0)
__device__ __forceinline__ u32 pk_bf_trunc(float hi, float lo) {
    return __builtin_amdgcn_perm(__float_as_uint(hi), __float_as_uint(lo), 0x07060302u);
}

// ---------------- Kernel 0: weight conversion fp32 -> bf16 ----------------
__global__ void wconv_kernel(const float* __restrict__ Wq, const float* __restrict__ Wk,
                             const float* __restrict__ Wv, const float* __restrict__ Wg,
                             const float* __restrict__ Wo, u16* __restrict__ wbf) {
    int idx = blockIdx.x * blockDim.x + threadIdx.x;  // 0..16383
    wbf[0 * 16384 + idx] = f2bf(Wq[idx]);
    wbf[1 * 16384 + idx] = f2bf(Wk[idx]);
    wbf[2 * 16384 + idx] = f2bf(Wv[idx]);
    wbf[3 * 16384 + idx] = f2bf(Wg[idx]);
    wbf[4 * 16384 + idx] = f2bf(Wo[idx]);
}

// ---------------- Kernel 1: fused LN + QKVG projection + attention ----------------
// 512 threads (8 waves), LDS ~66 KB -> 2 blocks/CU = 4 waves/SIMD.
// smem u16 layout:
//   [0, 9216)      : UNION  Phase A Xs (64x136=8704)  /  Phase B per-wave bufs (8 x 1152)
//   [9216, 22016)  : Ks 320x40
//   [22016, 32512) : VTs 32x328
#define KS_OFF 9216
#define VTS_OFF 22016
#define PB_W 1152   // per-wave: Q-transpose (16x40) then P-chunks (16x72)

__global__ __launch_bounds__(512, 4)
void attn_kernel(const float* __restrict__ pair,
                 const float* __restrict__ norm_w,
                 const float* __restrict__ norm_b,
                 const float* __restrict__ bg,
                 const float* __restrict__ Wb,
                 const u16* __restrict__ wbf,
                 u16* __restrict__ Obf,
                 u16* __restrict__ Gg) {
    const int l = blockIdx.x >> 2;
    const int h = blockIdx.x & 3;
    const int tid = threadIdx.x;
    const int wave = tid >> 6;
    const int lane = tid & 63;
    const int i_lo = lane & 15;
    const int q = lane >> 4;

    __shared__ __align__(16) u16 smem[32512];
    __shared__ __align__(16) float biasLds[320];  // bias[j] * log2e
    __shared__ __align__(16) float wls[384];      // norm_w | norm_b | Wb[h]

    if (tid < 96) {
        int a = tid >> 5;
        int t = tid & 31;
        const float* src = (a == 0) ? norm_w : (a == 1) ? norm_b : (Wb + h * 128);
        f32x4 v = *(const f32x4*)(src + t * 4);
        *(f32x4*)&wls[a * 128 + t * 4] = v;
    }

    float bg0 = bg[h * 32 + i_lo];
    float bg1 = bg[h * 32 + 16 + i_lo];

    __syncthreads();  // wls visible

    const int row_g = tid >> 3;        // 0..63 (8 lanes per row)
    const int c8 = tid & 7;            // 16-col octant
    const int wrow = (wave & 3) * 16;  // MFMA row strip within tile
    const int nth_flip = wave >> 2;    // parity: wave w does Q,K on tiles with t&1 == w>>2

    u32 qkeep[3][4];  // per-strip Q fragment, packed bf16 (rows q*4+{2rr,2rr+1}, d-half dd)

    // ---------- Phase A: LN + projections, 5 tiles of 64 rows, all 8 waves active ----------
#pragma unroll 1
    for (int t = 0; t < 5; ++t) {
        const int j0 = t * 64;
        const float* prow = pair + ((size_t)(l * 320 + j0 + row_g)) * 128 + c8 * 16;
        f32x4 pr[4];
#pragma unroll
        for (int u = 0; u < 4; ++u) pr[u] = *(const f32x4*)(prow + u * 4);

        float s = 0.f, s2 = 0.f, bd = 0.f;
#pragma unroll
        for (int u = 0; u < 4; ++u) {
            f32x4 p = pr[u];
            f32x4 wb4 = *(const f32x4*)&wls[256 + c8 * 16 + u * 4];
            s += p[0] + p[1] + p[2] + p[3];
            s2 += p[0] * p[0] + p[1] * p[1] + p[2] * p[2] + p[3] * p[3];
            bd += p[0] * wb4[0] + p[1] * wb4[1] + p[2] * wb4[2] + p[3] * wb4[3];
        }
        s += __shfl_xor(s, 1);   s += __shfl_xor(s, 2);   s += __shfl_xor(s, 4);
        s2 += __shfl_xor(s2, 1); s2 += __shfl_xor(s2, 2); s2 += __shfl_xor(s2, 4);
        bd += __shfl_xor(bd, 1); bd += __shfl_xor(bd, 2); bd += __shfl_xor(bd, 4);
        float mu = s * 0.0078125f;
        float var = s2 * 0.0078125f - mu * mu;
        float rs = rsqrtf(var + 1e-5f);

        __syncthreads();  // previous tile's Xs reads done
#pragma unroll
        for (int u = 0; u < 4; ++u) {
            f32x4 p = pr[u];
            f32x4 w4 = *(const f32x4*)&wls[0 + c8 * 16 + u * 4];
            f32x4 b4 = *(const f32x4*)&wls[128 + c8 * 16 + u * 4];
            ushort4 xv;
            xv.x = f2bf((p[0] - mu) * rs * w4[0] + b4[0]);
            xv.y = f2bf((p[1] - mu) * rs * w4[1] + b4[1]);
            xv.z = f2bf((p[2] - mu) * rs * w4[2] + b4[2]);
            xv.w = f2bf((p[3] - mu) * rs * w4[3] + b4[3]);
            *(ushort4*)&smem[row_g * 136 + c8 * 16 + u * 4] = xv;
        }
        if (c8 == 0) biasLds[j0 + row_g] = bd * LOG2E;
        __syncthreads();

        // projection: wave does (Q,K) or (V,G) half for rows [wrow, wrow+16)
        const int nth = (t & 1) ^ nth_flip;
        f32x4 acc[4];
#pragma unroll
        for (int n2 = 0; n2 < 4; ++n2) acc[n2] = (f32x4){0.f, 0.f, 0.f, 0.f};
#pragma unroll
        for (int kc = 0; kc < 4; ++kc) {
            bf16x8 a = *(const bf16x8*)&smem[(wrow + i_lo) * 136 + kc * 32 + q * 8];
#pragma unroll
            for (int n2 = 0; n2 < 4; ++n2) {
                int nt = nth * 4 + n2;  // 0,1=Q 2,3=K 4,5=V 6,7=G
                bf16x8 wf = *(const bf16x8*)&wbf[(nt >> 1) * 16384 +
                                                 (h * 32 + (nt & 1) * 16 + i_lo) * 128 + kc * 32 + q * 8];
                acc[n2] = __builtin_amdgcn_mfma_f32_16x16x32_bf16(a, wf, acc[n2], 0, 0, 0);
            }
        }
        const int jrow = j0 + wrow + q * 4;
        if (nth == 0) {
            const int ti = t >> 1;  // strip index for this wave
#pragma unroll
            for (int dd = 0; dd < 2; ++dd)
#pragma unroll
                for (int rr = 0; rr < 2; ++rr)
                    qkeep[ti][dd * 2 + rr] =
                        (u32)f2bf(acc[dd][rr * 2]) | ((u32)f2bf(acc[dd][rr * 2 + 1]) << 16);
#pragma unroll
            for (int n2 = 2; n2 < 4; ++n2)
#pragma unroll
                for (int r = 0; r < 4; ++r)
                    smem[KS_OFF + (jrow + r) * 40 + (n2 & 1) * 16 + i_lo] = f2bf(acc[n2][r]);
        } else {
#pragma unroll
            for (int n2 = 0; n2 < 2; ++n2)
#pragma unroll
                for (int r = 0; r < 4; ++r)
                    smem[VTS_OFF + (n2 * 16 + i_lo) * 328 + jrow + r] = f2bf(acc[n2][r]);
#pragma unroll
            for (int n2 = 2; n2 < 4; ++n2)
#pragma unroll
                for (int r = 0; r < 4; ++r) {
                    float z = acc[n2][r] + ((n2 & 1) ? bg1 : bg0);
                    float g = 1.0f / (1.0f + exp2f(-z * LOG2E));
                    Gg[((size_t)((l * 4 + h) * 320 + jrow + r)) * 32 + (n2 & 1) * 16 + i_lo] = f2bf(g);
                }
        }
    }
    __syncthreads();  // Ks/VTs/bias visible; Xs region free for per-wave buffers

    // ---------- Phase B: wave w handles strips w, w+8, w+16(w<4) ----------
    const float SC = 0.17677669529663687f * LOG2E;  // Dh^-0.5 * log2e
    const f32x4 zero4 = {0.f, 0.f, 0.f, 0.f};
    u16* pb = smem + wave * PB_W;
    const int nstrip = (wave < 4) ? 3 : 2;
#pragma unroll 1
    for (int t2 = 0; t2 < nstrip; ++t2) {
        const int i0 = (wave + 8 * t2) * 16;
        // Q transpose: C-layout regs -> qb[row][d] (stride 40) -> B-frag read
#pragma unroll
        for (int dd = 0; dd < 2; ++dd)
#pragma unroll
            for (int rr = 0; rr < 2; ++rr) {
                u32 v = qkeep[t2][dd * 2 + rr];
                pb[(q * 4 + rr * 2) * 40 + dd * 16 + i_lo] = (u16)v;
                pb[(q * 4 + rr * 2 + 1) * 40 + dd * 16 + i_lo] = (u16)(v >> 16);
            }
        bf16x8 qf = *(const bf16x8*)&pb[i_lo * 40 + q * 8];

        f32x4 oacc[2];
        oacc[0] = zero4; oacc[1] = zero4;
        float sum = 0.f;
        // 5 chunks of 64 j: QK -> exp -> P to pb -> PV
#pragma unroll 1
        for (int c = 0; c < 5; ++c) {
            f32x4 sc4[4];
#pragma unroll
            for (int jt = 0; jt < 4; ++jt) {
                bf16x8 kf = *(const bf16x8*)&smem[KS_OFF + (c * 64 + jt * 16 + i_lo) * 40 + q * 8];
                sc4[jt] = __builtin_amdgcn_mfma_f32_16x16x32_bf16(kf, qf, zero4, 0, 0, 0);
            }
#pragma unroll
            for (int jt = 0; jt < 4; ++jt) {
                f32x4 b4 = *(const f32x4*)&biasLds[c * 64 + jt * 16 + q * 4];
#pragma unroll
                for (int r = 0; r < 4; ++r) {
                    float p = exp2f(sc4[jt][r] * SC + b4[r]);
                    sc4[jt][r] = p;
                    sum += p;
                }
            }
#pragma unroll
            for (int jt = 0; jt < 4; ++jt) {
                u32x2 pk;
                pk.x = pk_bf_trunc(sc4[jt][1], sc4[jt][0]);
                pk.y = pk_bf_trunc(sc4[jt][3], sc4[jt][2]);
                *(u32x2*)&pb[i_lo * 72 + jt * 16 + q * 4] = pk;
            }
#pragma unroll
            for (int kt2 = 0; kt2 < 2; ++kt2) {
                bf16x8 pf = *(const bf16x8*)&pb[i_lo * 72 + kt2 * 32 + q * 8];
#pragma unroll
                for (int mt = 0; mt < 2; ++mt) {
                    bf16x8 vf = *(const bf16x8*)&smem[VTS_OFF + (mt * 16 + i_lo) * 328 +
                                                      c * 64 + kt2 * 32 + q * 8];
                    oacc[mt] = __builtin_amdgcn_mfma_f32_16x16x32_bf16(vf, pf, oacc[mt], 0, 0, 0);
                }
            }
        }
        sum += __shfl_xor(sum, 16);
        sum += __shfl_xor(sum, 32);
        float rinv = 1.0f / sum;
        // epilogue: lane holds O^T[d = mt*16+q*4+r][i = i0+i_lo]; normalize, store (gate in outproj)
#pragma unroll
        for (int mt = 0; mt < 2; ++mt) {
            u32x2 pk;
            pk.x = pk_bf_trunc(oacc[mt][1] * rinv, oacc[mt][0] * rinv);
            pk.y = pk_bf_trunc(oacc[mt][3] * rinv, oacc[mt][2] * rinv);
            *(u32x2*)&Obf[((size_t)(l * 320 + i0 + i_lo)) * 128 + h * 32 + mt * 16 + q * 4] = pk;
        }
    }
}

// ---------------- Kernel 2: out = pair + (g .* O) @ Wo^T + bo ----------------
__global__ __launch_bounds__(256)
void outproj_kernel(const float* __restrict__ pair,
                    const float* __restrict__ bo,
                    const u16* __restrict__ Obf,
                    const u16* __restrict__ Gg,
                    const u16* __restrict__ wbf,
                    float* __restrict__ out) {
    const int tid = threadIdx.x;
    const int wave = tid >> 6;
    const int lane = tid & 63;
    const int i_lo = lane & 15;
    const int q = lane >> 4;
    const int blk = blockIdx.x;
    const int mrow = blk * 64 + wave * 16;
    const int lidx = blk / 5;                      // 64-row blocks never straddle l (320 = 5*64)
    const int irow = mrow - lidx * 320 + i_lo;     // row index within l
    const u16* Wo = wbf + 4 * 16384;

    // A-frag = O .* g (elementwise bf16, kc indexes head h = kc)
    bf16x8 of[4];
#pragma unroll
    for (int kc = 0; kc < 4; ++kc) {
        union { bf16x8 v; u32 u[4]; } A, G, R;
        A.v = *(const bf16x8*)&Obf[((size_t)(mrow + i_lo)) * 128 + kc * 32 + q * 8];
        G.v = *(const bf16x8*)&Gg[((size_t)((lidx * 4 + kc) * 320 + irow)) * 32 + q * 8];
#pragma unroll
        for (int k4 = 0; k4 < 4; ++k4) {
            float lo = __uint_as_float(A.u[k4] << 16) * __uint_as_float(G.u[k4] << 16);
            float hi = __uint_as_float(A.u[k4] & 0xffff0000u) * __uint_as_float(G.u[k4] & 0xffff0000u);
            R.u[k4] = pk_bf_trunc(hi, lo);
        }
        of[kc] = R.v;
    }

    f32x4 acc[8];
#pragma unroll
    for (int nt = 0; nt < 8; ++nt) acc[nt] = (f32x4){0.f, 0.f, 0.f, 0.f};
#pragma unroll
    for (int nt = 0; nt < 8; ++nt) {
#pragma unroll
        for (int kc = 0; kc < 4; ++kc) {
            bf16x8 wf = *(const bf16x8*)&Wo[(nt * 16 + i_lo) * 128 + kc * 32 + q * 8];
            acc[nt] = __builtin_amdgcn_mfma_f32_16x16x32_bf16(wf, of[kc], acc[nt], 0, 0, 0);
        }
    }
    // lane holds out[row = mrow+i_lo][col = nt*16 + q*4 + r] -> f32x4
#pragma unroll
    for (int nt = 0; nt < 8; ++nt) {
        size_t idx = ((size_t)(mrow + i_lo)) * 128 + nt * 16 + q * 4;
        f32x4 p4 = *(const f32x4*)&pair[idx];
        f32x4 b4 = *(const f32x4*)&bo[nt * 16 + q * 4];
        f32x4 o4;
        o4[0] = acc[nt][0] + p4[0] + b4[0];
        o4[1] = acc[nt][1] + p4[1] + b4[1];
        o4[2] = acc[nt][2] + p4[2] + b4[2];
        o4[3] = acc[nt][3] + p4[3] + b4[3];
        *(f32x4*)&out[idx] = o4;
    }
}

extern "C" void kernel_launch(void* const* d_in, const int* in_sizes, int n_in,
                              void* d_out, int out_size, void* d_ws, size_t ws_size,
                              hipStream_t stream) {
    const float* pair   = (const float*)d_in[0];
    const float* norm_w = (const float*)d_in[1];
    const float* norm_b = (const float*)d_in[2];
    const float* Wq     = (const float*)d_in[3];
    const float* Wk     = (const float*)d_in[4];
    const float* Wv     = (const float*)d_in[5];
    const float* Wg     = (const float*)d_in[6];
    const float* bg     = (const float*)d_in[7];
    const float* Wo     = (const float*)d_in[8];
    const float* bo     = (const float*)d_in[9];
    const float* Wb     = (const float*)d_in[10];

    u16* wbf = (u16*)d_ws;                 // 5 * 128*128 bf16 weights
    u16* Obf = wbf + 5 * 16384;            // 102400 x 128 bf16 (ungated, normalized)
    u16* Gg  = Obf + (size_t)102400 * 128; // (l,h,i,d) 1280 x 320 x 32 bf16 gates
    float* out = (float*)d_out;

    wconv_kernel<<<64, 256, 0, stream>>>(Wq, Wk, Wv, Wg, Wo, wbf);
    attn_kernel<<<320 * 4, 512, 0, stream>>>(pair, norm_w, norm_b, bg, Wb, wbf, Obf, Gg);
    outproj_kernel<<<1600, 256, 0, stream>>>(pair, bo, Obf, Gg, wbf, out);
}